// Round 8
// baseline (608.766 us; speedup 1.0000x reference)
//
#include <hip/hip_runtime.h>
#include <math.h>

constexpr float EPS = 1e-5f;
constexpr float SCALE = 0.08838834764831845f; // 1/sqrt(128)

using f32x4  = __attribute__((ext_vector_type(4))) float;
using bf16x8 = __attribute__((ext_vector_type(8))) short;
using us8    = __attribute__((ext_vector_type(8))) unsigned short;

__device__ __forceinline__ unsigned short f2b_rne(float f) {
    unsigned int x = __float_as_uint(f);
    return (unsigned short)((x + 0x7fffu + ((x >> 16) & 1u)) >> 16);
}

// ================= one-time weight split: fp32 -> (hi, lo) bf16 planes =======
// Wp (24576) | Wk (16384) | Wv (16384) packed contiguously.
__global__ __launch_bounds__(256) void split_weights_kernel(
    const float* __restrict__ Wp, const float* __restrict__ Wk,
    const float* __restrict__ Wv, unsigned short* __restrict__ hi,
    unsigned short* __restrict__ lo)
{
    int idx = blockIdx.x * 256 + threadIdx.x; // 57344 total
    float v;
    if (idx < 24576)      v = Wp[idx];
    else if (idx < 40960) v = Wk[idx - 24576];
    else                  v = Wv[idx - 40960];
    unsigned int bits = __float_as_uint(v);
    hi[idx] = (unsigned short)(bits >> 16);
    lo[idx] = f2b_rne(v - __uint_as_float(bits & 0xffff0000u));
}

// ====== FUSED: X = LN(patch@Wp^T+bp); k = X@Wk^T+bk; v = X@Wv^T+bv ===========
// 512 thr = 8 waves, 128 rows/block, 1024 blocks. Weight B-fragments are read
// DIRECTLY from global (weights are L2-hot: 160 KB total) — no LDS staging, no
// barrier in either K-loop. X never goes to HBM: it is transposed C-layout ->
// A-layout through a per-wave-private LDS slice (stride 136 shorts: 2-way max
// bank aliasing). Split precision (hi+lo bf16, 3 MFMAs/product) throughout.
__global__ __launch_bounds__(512, 4) void gemm_fused_kernel(
    const float* __restrict__ patch,
    const unsigned short* __restrict__ wp_hi, const unsigned short* __restrict__ wp_lo,
    const unsigned short* __restrict__ wk_hi, const unsigned short* __restrict__ wk_lo,
    const unsigned short* __restrict__ wv_hi, const unsigned short* __restrict__ wv_lo,
    const float* __restrict__ bp, const float* __restrict__ g_in,
    const float* __restrict__ b_in, const float* __restrict__ bk,
    const float* __restrict__ bv,
    float* __restrict__ kout, float* __restrict__ vout)
{
    __shared__ __align__(16) unsigned short XT[2][8][16][136]; // ~69.6 KB

    const int tid  = threadIdx.x;
    const int lane = tid & 63, w = tid >> 6;
    const int ln15 = lane & 15, quad = lane >> 4;
    const int m0   = blockIdx.x * 128;
    const int row  = m0 + w * 16 + ln15;

    // ---- phase A: A-fragments from patch (fp32 -> hi/lo bf16) ----
    bf16x8 ah[6], al[6];
#pragma unroll
    for (int kb = 0; kb < 6; kb++) {
        const float* ap = patch + (size_t)row * 192 + kb * 32 + quad * 8;
        float4 x = *(const float4*)ap;
        float4 y = *(const float4*)(ap + 4);
        float vv[8] = {x.x, x.y, x.z, x.w, y.x, y.y, y.z, y.w};
        us8 h, l;
#pragma unroll
        for (int j = 0; j < 8; j++) {
            unsigned int bits = __float_as_uint(vv[j]);
            h[j] = (unsigned short)(bits >> 16);
            l[j] = f2b_rne(vv[j] - __uint_as_float(bits & 0xffff0000u));
        }
        ah[kb] = (bf16x8)h; al[kb] = (bf16x8)l;
    }

    f32x4 acc[8];
#pragma unroll
    for (int nt = 0; nt < 8; nt++)
#pragma unroll
        for (int r = 0; r < 4; r++) acc[nt][r] = 0.f;

#pragma unroll
    for (int kb = 0; kb < 6; kb++)
#pragma unroll
        for (int nt = 0; nt < 8; nt++) {
            size_t o = (size_t)(nt * 16 + ln15) * 192 + kb * 32 + quad * 8;
            bf16x8 bh = *(const bf16x8*)&wp_hi[o];
            bf16x8 bl = *(const bf16x8*)&wp_lo[o];
            acc[nt] = __builtin_amdgcn_mfma_f32_16x16x32_bf16(ah[kb], bh, acc[nt], 0, 0, 0);
            acc[nt] = __builtin_amdgcn_mfma_f32_16x16x32_bf16(ah[kb], bl, acc[nt], 0, 0, 0);
            acc[nt] = __builtin_amdgcn_mfma_f32_16x16x32_bf16(al[kb], bh, acc[nt], 0, 0, 0);
        }

    // ---- bias + LN over 128 cols (quad-level shuffle reduce) ----
    float bb[8], gg[8], be[8];
#pragma unroll
    for (int nt = 0; nt < 8; nt++) {
        int col = nt * 16 + ln15;
        bb[nt] = bp[col]; gg[nt] = g_in[col]; be[nt] = b_in[col];
    }
#pragma unroll
    for (int nt = 0; nt < 8; nt++)
#pragma unroll
        for (int r = 0; r < 4; r++) acc[nt][r] += bb[nt];

#pragma unroll
    for (int r = 0; r < 4; r++) {
        float s = 0.f, s2 = 0.f;
#pragma unroll
        for (int nt = 0; nt < 8; nt++) { float v = acc[nt][r]; s += v; s2 += v * v; }
#pragma unroll
        for (int off = 1; off < 16; off <<= 1) {
            s  += __shfl_xor(s,  off, 64);
            s2 += __shfl_xor(s2, off, 64);
        }
        float m = s * (1.f / 128.f);
        float rs = rsqrtf(s2 * (1.f / 128.f) - m * m + EPS);
        // normalize + split-store into the wave's private LDS transpose slice
#pragma unroll
        for (int nt = 0; nt < 8; nt++) {
            float v = (acc[nt][r] - m) * rs * gg[nt] + be[nt];
            unsigned int bits = __float_as_uint(v);
            int rr = quad * 4 + r, cc = nt * 16 + ln15;
            XT[0][w][rr][cc] = (unsigned short)(bits >> 16);
            XT[1][w][rr][cc] = f2b_rne(v - __uint_as_float(bits & 0xffff0000u));
        }
    }
    __syncthreads();

    // ---- phase B: read X A-fragments back, k & v GEMMs ----
    bf16x8 xh[4], xl[4];
#pragma unroll
    for (int kb = 0; kb < 4; kb++) {
        xh[kb] = *(const bf16x8*)&XT[0][w][ln15][kb * 32 + quad * 8];
        xl[kb] = *(const bf16x8*)&XT[1][w][ln15][kb * 32 + quad * 8];
    }

    f32x4 kacc[8], vacc[8];
#pragma unroll
    for (int nt = 0; nt < 8; nt++)
#pragma unroll
        for (int r = 0; r < 4; r++) { kacc[nt][r] = 0.f; vacc[nt][r] = 0.f; }

#pragma unroll
    for (int kb = 0; kb < 4; kb++)
#pragma unroll
        for (int nt = 0; nt < 8; nt++) {
            size_t o = (size_t)(nt * 16 + ln15) * 128 + kb * 32 + quad * 8;
            bf16x8 kh = *(const bf16x8*)&wk_hi[o];
            bf16x8 kl = *(const bf16x8*)&wk_lo[o];
            bf16x8 vh = *(const bf16x8*)&wv_hi[o];
            bf16x8 vl = *(const bf16x8*)&wv_lo[o];
            kacc[nt] = __builtin_amdgcn_mfma_f32_16x16x32_bf16(xh[kb], kh, kacc[nt], 0, 0, 0);
            kacc[nt] = __builtin_amdgcn_mfma_f32_16x16x32_bf16(xh[kb], kl, kacc[nt], 0, 0, 0);
            kacc[nt] = __builtin_amdgcn_mfma_f32_16x16x32_bf16(xl[kb], kh, kacc[nt], 0, 0, 0);
            vacc[nt] = __builtin_amdgcn_mfma_f32_16x16x32_bf16(xh[kb], vh, vacc[nt], 0, 0, 0);
            vacc[nt] = __builtin_amdgcn_mfma_f32_16x16x32_bf16(xh[kb], vl, vacc[nt], 0, 0, 0);
            vacc[nt] = __builtin_amdgcn_mfma_f32_16x16x32_bf16(xl[kb], vh, vacc[nt], 0, 0, 0);
        }

    float bbk[8], bbv[8];
#pragma unroll
    for (int nt = 0; nt < 8; nt++) {
        int col = nt * 16 + ln15;
        bbk[nt] = bk[col]; bbv[nt] = bv[col];
    }
#pragma unroll
    for (int nt = 0; nt < 8; nt++)
#pragma unroll
        for (int r = 0; r < 4; r++) {
            size_t rowt = (size_t)(m0 + w * 16 + quad * 4 + r);
            kout[rowt * 128 + nt * 16 + ln15] = kacc[nt][r] + bbk[nt];
            vout[rowt * 128 + nt * 16 + ln15] = vacc[nt][r] + bbv[nt];
        }
}

// =================== init slots + LN + q0 (R3 verbatim) ======================
__global__ __launch_bounds__(128) void init_lnq_kernel(
    const float* __restrict__ noise, const float* __restrict__ smu,
    const float* __restrict__ sls, const float* __restrict__ g_s,
    const float* __restrict__ b_s, const float* __restrict__ Wq,
    const float* __restrict__ bq, float* __restrict__ slots,
    float* __restrict__ q)
{
    __shared__ float s_l[128];
    __shared__ float red[4];
    const int row = blockIdx.x, tid = threadIdx.x;
    const int k = row % 3;
    float x = smu[k * 128 + tid] + expf(sls[k * 128 + tid]) * noise[row * 128 + tid];
    slots[row * 128 + tid] = x;

    float s = x, s2 = x * x;
#pragma unroll
    for (int off = 32; off >= 1; off >>= 1) {
        s += __shfl_down(s, off, 64); s2 += __shfl_down(s2, off, 64);
    }
    if ((tid & 63) == 0) { red[tid >> 6] = s; red[2 + (tid >> 6)] = s2; }
    __syncthreads();
    float S = red[0] + red[1], S2 = red[2] + red[3];
    float m = S * (1.f / 128.f);
    float r = rsqrtf(S2 * (1.f / 128.f) - m * m + EPS);
    s_l[tid] = (x - m) * r * g_s[tid] + b_s[tid];
    __syncthreads();

    const float4* wr = (const float4*)&Wq[(size_t)tid * 128];
    float a = bq[tid];
#pragma unroll 8
    for (int d4 = 0; d4 < 32; d4++) {
        float4 w = wr[d4];
        a += s_l[4 * d4] * w.x + s_l[4 * d4 + 1] * w.y
           + s_l[4 * d4 + 2] * w.z + s_l[4 * d4 + 3] * w.w;
    }
    q[row * 128 + tid] = a;
}

// ===== attention (R3 verbatim): 64-token chunks, 2048 blocks x 256 thr =======
__global__ __launch_bounds__(256) void attn_kernel(
    const float* __restrict__ q, const float* __restrict__ kbuf,
    const float* __restrict__ vbuf, float* __restrict__ upd_part,
    float* __restrict__ attn_out, int write_attn)
{
    __shared__ float q_l[3][128];
    __shared__ __align__(16) float kv[64][132];
    __shared__ float lg[3][64];
    __shared__ float w_l[3][64];
    const int b = blockIdx.y, chunk = blockIdx.x, n0 = chunk * 64, tid = threadIdx.x;

    for (int idx = tid; idx < 384; idx += 256)
        q_l[idx >> 7][idx & 127] = q[b * 384 + idx];

    const float4* kg = (const float4*)(kbuf + ((size_t)b * 1024 + n0) * 128);
    for (int idx = tid; idx < 2048; idx += 256) {
        int n = idx >> 5, c = (idx & 31) * 4;
        *(float4*)&kv[n][c] = kg[idx];
    }
    __syncthreads();

    { // logits: thread = (token n, quarter q4); all 256 threads active
        int n = tid >> 2, q4 = tid & 3;
        const float* kr = &kv[n][q4 * 32];
        const float* q0 = &q_l[0][q4 * 32];
        const float* q1 = &q_l[1][q4 * 32];
        const float* q2 = &q_l[2][q4 * 32];
        float p0 = 0.f, p1 = 0.f, p2 = 0.f;
#pragma unroll 8
        for (int i = 0; i < 32; i++) {
            float vv = kr[i];
            p0 += q0[i] * vv; p1 += q1[i] * vv; p2 += q2[i] * vv;
        }
        p0 += __shfl_xor(p0, 1, 64); p0 += __shfl_xor(p0, 2, 64);
        p1 += __shfl_xor(p1, 1, 64); p1 += __shfl_xor(p1, 2, 64);
        p2 += __shfl_xor(p2, 1, 64); p2 += __shfl_xor(p2, 2, 64);
        if (q4 == 0) {
            lg[0][n] = p0 * SCALE; lg[1][n] = p1 * SCALE; lg[2][n] = p2 * SCALE;
        }
    }
    __syncthreads();

    if (tid < 64) { // softmax over the 3 slots for token n=tid
        float l0 = lg[0][tid], l1 = lg[1][tid], l2 = lg[2][tid];
        float m = fmaxf(l0, fmaxf(l1, l2));
        float e0 = expf(l0 - m), e1 = expf(l1 - m), e2 = expf(l2 - m);
        float inv = 1.f / (e0 + e1 + e2);
        w_l[0][tid] = e0 * inv; w_l[1][tid] = e1 * inv; w_l[2][tid] = e2 * inv;
        if (write_attn) {
            attn_out[b * 3072 + n0 + tid]        = e0 * inv;
            attn_out[b * 3072 + 1024 + n0 + tid] = e1 * inv;
            attn_out[b * 3072 + 2048 + n0 + tid] = e2 * inv;
        }
    }
    const float4* vg = (const float4*)(vbuf + ((size_t)b * 1024 + n0) * 128);
    for (int idx = tid; idx < 2048; idx += 256) {
        int n = idx >> 5, c = (idx & 31) * 4;
        *(float4*)&kv[n][c] = vg[idx];
    }
    __syncthreads();

    if (tid < 128) {
        float p0 = 0.f, p1 = 0.f, p2 = 0.f;
#pragma unroll 8
        for (int n = 0; n < 64; n++) {
            float vv = kv[n][tid];
            p0 += w_l[0][n] * vv; p1 += w_l[1][n] * vv; p2 += w_l[2][n] * vv;
        }
        size_t base = (((size_t)b * 16 + chunk) * 3) * 128 + tid;
        upd_part[base]       = p0;
        upd_part[base + 128] = p1;
        upd_part[base + 256] = p2;
    }
}

// ====== GRU + LN + MLP + residual (+ LN_s + q), R3 verbatim, 128 thr =========
__global__ __launch_bounds__(128) void gru_mlp_kernel(
    const float* __restrict__ slots_in, const float* __restrict__ upd_part,
    const float* __restrict__ Wih, const float* __restrict__ bih,
    const float* __restrict__ Whh, const float* __restrict__ bhh,
    const float* __restrict__ g_m, const float* __restrict__ b_m,
    const float* __restrict__ W1, const float* __restrict__ b1,
    const float* __restrict__ W2, const float* __restrict__ b2,
    const float* __restrict__ g_s, const float* __restrict__ b_s,
    const float* __restrict__ Wq, const float* __restrict__ bq,
    float* __restrict__ slots_out, float* __restrict__ q_out, int write_q)
{
    __shared__ float u_l[128], h_l[128], n_l[128], hid_l[256];
    __shared__ float red[4];
    const int row = blockIdx.x, tid = threadIdx.x;
    const int bb_ = row / 3, ss = row - bb_ * 3;

    float hprev = slots_in[row * 128 + tid];
    float u = 0.f;
    {
        const float* up = upd_part + (((size_t)bb_ * 16) * 3 + ss) * 128 + tid;
#pragma unroll
        for (int c = 0; c < 16; c++) u += up[(size_t)c * 384];
    }
    u_l[tid] = u;
    h_l[tid] = hprev;
    __syncthreads();

    float ir = bih[tid], iz = bih[128 + tid], in_ = bih[256 + tid];
    float hr = bhh[tid], hz = bhh[128 + tid], hn = bhh[256 + tid];
    const float4* wi0 = (const float4*)&Wih[(size_t)tid * 128];
    const float4* wi1 = (const float4*)&Wih[(size_t)(128 + tid) * 128];
    const float4* wi2 = (const float4*)&Wih[(size_t)(256 + tid) * 128];
    const float4* wh0 = (const float4*)&Whh[(size_t)tid * 128];
    const float4* wh1 = (const float4*)&Whh[(size_t)(128 + tid) * 128];
    const float4* wh2 = (const float4*)&Whh[(size_t)(256 + tid) * 128];
#pragma unroll 4
    for (int d4 = 0; d4 < 32; d4++) {
        float u0 = u_l[4 * d4], u1 = u_l[4 * d4 + 1], u2 = u_l[4 * d4 + 2], u3 = u_l[4 * d4 + 3];
        float h0 = h_l[4 * d4], h1 = h_l[4 * d4 + 1], h2 = h_l[4 * d4 + 2], h3 = h_l[4 * d4 + 3];
        float4 w;
        w = wi0[d4]; ir  += u0 * w.x + u1 * w.y + u2 * w.z + u3 * w.w;
        w = wi1[d4]; iz  += u0 * w.x + u1 * w.y + u2 * w.z + u3 * w.w;
        w = wi2[d4]; in_ += u0 * w.x + u1 * w.y + u2 * w.z + u3 * w.w;
        w = wh0[d4]; hr  += h0 * w.x + h1 * w.y + h2 * w.z + h3 * w.w;
        w = wh1[d4]; hz  += h0 * w.x + h1 * w.y + h2 * w.z + h3 * w.w;
        w = wh2[d4]; hn  += h0 * w.x + h1 * w.y + h2 * w.z + h3 * w.w;
    }
    float r = 1.f / (1.f + expf(-(ir + hr)));
    float z = 1.f / (1.f + expf(-(iz + hz)));
    float nn = tanhf(in_ + r * hn);
    float hnew = (1.f - z) * nn + z * hprev;

    float s = hnew, s2 = hnew * hnew;
#pragma unroll
    for (int off = 32; off >= 1; off >>= 1) {
        s += __shfl_down(s, off, 64); s2 += __shfl_down(s2, off, 64);
    }
    if ((tid & 63) == 0) { red[tid >> 6] = s; red[2 + (tid >> 6)] = s2; }
    __syncthreads();
    float S = red[0] + red[1], S2 = red[2] + red[3];
    float m1 = S * (1.f / 128.f);
    float r1 = rsqrtf(S2 * (1.f / 128.f) - m1 * m1 + EPS);
    n_l[tid] = (hnew - m1) * r1 * g_m[tid] + b_m[tid];
    __syncthreads();

    float a0 = b1[tid], a1 = b1[128 + tid];
    const float4* w1a = (const float4*)&W1[(size_t)tid * 128];
    const float4* w1b = (const float4*)&W1[(size_t)(128 + tid) * 128];
#pragma unroll 4
    for (int d4 = 0; d4 < 32; d4++) {
        float x0 = n_l[4 * d4], x1 = n_l[4 * d4 + 1], x2 = n_l[4 * d4 + 2], x3 = n_l[4 * d4 + 3];
        float4 wa = w1a[d4], wb = w1b[d4];
        a0 += x0 * wa.x + x1 * wa.y + x2 * wa.z + x3 * wa.w;
        a1 += x0 * wb.x + x1 * wb.y + x2 * wb.z + x3 * wb.w;
    }
    a0 = 0.5f * a0 * (1.f + erff(a0 * 0.70710678118654752f));
    a1 = 0.5f * a1 * (1.f + erff(a1 * 0.70710678118654752f));
    hid_l[tid] = a0; hid_l[128 + tid] = a1;
    __syncthreads();

    float o = b2[tid];
    const float4* w2r = (const float4*)&W2[(size_t)tid * 256];
#pragma unroll 4
    for (int d4 = 0; d4 < 64; d4++) {
        float4 w = w2r[d4];
        o += hid_l[4 * d4] * w.x + hid_l[4 * d4 + 1] * w.y
           + hid_l[4 * d4 + 2] * w.z + hid_l[4 * d4 + 3] * w.w;
    }
    float snew = hnew + o;
    slots_out[row * 128 + tid] = snew;

    if (write_q) {
        __syncthreads();
        float t = snew, t2 = snew * snew;
#pragma unroll
        for (int off = 32; off >= 1; off >>= 1) {
            t += __shfl_down(t, off, 64); t2 += __shfl_down(t2, off, 64);
        }
        if ((tid & 63) == 0) { red[tid >> 6] = t; red[2 + (tid >> 6)] = t2; }
        __syncthreads();
        float T = red[0] + red[1], T2 = red[2] + red[3];
        float m2 = T * (1.f / 128.f);
        float r2 = rsqrtf(T2 * (1.f / 128.f) - m2 * m2 + EPS);
        n_l[tid] = (snew - m2) * r2 * g_s[tid] + b_s[tid];
        __syncthreads();
        const float4* wr = (const float4*)&Wq[(size_t)tid * 128];
        float a = bq[tid];
#pragma unroll 8
        for (int d4 = 0; d4 < 32; d4++) {
            float4 w = wr[d4];
            a += n_l[4 * d4] * w.x + n_l[4 * d4 + 1] * w.y
               + n_l[4 * d4 + 2] * w.z + n_l[4 * d4 + 3] * w.w;
        }
        q_out[row * 128 + tid] = a;
    }
}

// ============================================================================
extern "C" void kernel_launch(void* const* d_in, const int* in_sizes, int n_in,
                              void* d_out, int out_size, void* d_ws, size_t ws_size,
                              hipStream_t stream)
{
    const float* patch   = (const float*)d_in[0];
    const float* noise   = (const float*)d_in[1];
    const float* slot_mu = (const float*)d_in[2];
    const float* slot_ls = (const float*)d_in[3];
    const float* Wp = (const float*)d_in[4];  const float* bp = (const float*)d_in[5];
    const float* g_in = (const float*)d_in[6]; const float* b_in = (const float*)d_in[7];
    const float* Wq = (const float*)d_in[8];  const float* bq = (const float*)d_in[9];
    const float* Wk = (const float*)d_in[10]; const float* bk = (const float*)d_in[11];
    const float* Wv = (const float*)d_in[12]; const float* bv = (const float*)d_in[13];
    const float* Wih = (const float*)d_in[14]; const float* bih = (const float*)d_in[15];
    const float* Whh = (const float*)d_in[16]; const float* bhh = (const float*)d_in[17];
    const float* g_s = (const float*)d_in[18]; const float* b_s = (const float*)d_in[19];
    const float* W1 = (const float*)d_in[20]; const float* b1 = (const float*)d_in[21];
    const float* W2 = (const float*)d_in[22]; const float* b2 = (const float*)d_in[23];
    const float* g_m = (const float*)d_in[24]; const float* b_m = (const float*)d_in[25];

    float* kbuf = (float*)d_ws;                                   // 16777216 f32
    float* vbuf = kbuf + 16777216;                                // 16777216 f32
    unsigned short* w_hi = (unsigned short*)(vbuf + 16777216);    // 57344 bf16
    unsigned short* w_lo = w_hi + 57344;                          // 57344 bf16
    unsigned short* wp_hi = w_hi,         * wp_lo = w_lo;
    unsigned short* wk_hi = w_hi + 24576, * wk_lo = w_lo + 24576;
    unsigned short* wv_hi = w_hi + 40960, * wv_lo = w_lo + 40960;
    float* slots = (float*)(w_lo + 57344);                        // 49152 f32
    float* qbuf  = slots + 49152;                                 // 49152 f32
    float* part  = qbuf + 49152;                                  // 786432 f32

    float* out_slots = (float*)d_out;                             // (B,K,H)
    float* out_attn  = (float*)d_out + 49152;                     // (B,K,N)

    split_weights_kernel<<<224, 256, 0, stream>>>(Wp, Wk, Wv, w_hi, w_lo);
    gemm_fused_kernel<<<1024, 512, 0, stream>>>(
        patch, wp_hi, wp_lo, wk_hi, wk_lo, wv_hi, wv_lo,
        bp, g_in, b_in, bk, bv, kbuf, vbuf);
    init_lnq_kernel<<<384, 128, 0, stream>>>(noise, slot_mu, slot_ls,
                                             g_s, b_s, Wq, bq, slots, qbuf);

    for (int it = 0; it < 3; it++) {
        attn_kernel<<<dim3(16, 128), 256, 0, stream>>>(
            qbuf, kbuf, vbuf, part, out_attn, it == 2 ? 1 : 0);
        gru_mlp_kernel<<<384, 128, 0, stream>>>(
            slots, part, Wih, bih, Whh, bhh, g_m, b_m, W1, b1, W2, b2,
            g_s, b_s, Wq, bq,
            (it == 2) ? out_slots : slots, qbuf, it == 2 ? 0 : 1);
    }
}